// Round 1
// baseline (194.450 us; speedup 1.0000x reference)
//
#include <hip/hip_runtime.h>
#include <math.h>

// GlobalAttention, algebraically restructured:
//   q is batch-independent (class_feature broadcast) -> fold q through Wkv_k:
//     logits[b,h,n] = qW[h,:] . LN(x[b,n,:]),  qW[h,:] = (scale*q[h,:]) @ Wkv[h*D:(h+1)*D, :]
//   fold softmax-weighted V through Wkv_v:
//     agg[b,h,:] = Wkv_v[h] @ s[b,h,:],  s[b,h,:] = sum_n p[b,h,n] * LN(x[b,n,:])
//   LN folded via per-row mu/rstd:
//     qW.LN(x) = rstd*(qWg.x - mu*sum(qWg)) + qW.beta        (qWg = qW*gamma)
//     s = gamma*(sum_n w_n x_n - u) + beta, w_n = p_n*rstd_n, u = sum p_n rstd_n mu_n
// => two streaming passes over features (256 MB each), memory-bound.

#define BB 16
#define NN 4096
#define CC 1024
#define HH 8
#define DD 128

constexpr float EPS_ = 1e-5f;
constexpr float SCALE_ = 0.03125f; // 1024^-0.5

__device__ __forceinline__ float wsum(float v) {
#pragma unroll
  for (int o = 32; o; o >>= 1) v += __shfl_xor(v, o, 64);
  return v;
}
__device__ __forceinline__ float wmax(float v) {
#pragma unroll
  for (int o = 32; o; o >>= 1) v = fmaxf(v, __shfl_xor(v, o, 64));
  return v;
}

// ---- k0a: LN(class_feature) -> ln_cf [1024], one block ----
__global__ __launch_bounds__(256) void k0a(const float* __restrict__ cf,
                                           const float* __restrict__ g,
                                           const float* __restrict__ be,
                                           float* __restrict__ ln_cf) {
  int t = threadIdx.x, lane = t & 63, wid = t >> 6;
  float x[4];
  float s = 0.f, s2 = 0.f;
#pragma unroll
  for (int j = 0; j < 4; ++j) {
    x[j] = cf[t * 4 + j];
    s += x[j];
    s2 += x[j] * x[j];
  }
  __shared__ float red[8];
  s = wsum(s);
  s2 = wsum(s2);
  if (lane == 0) { red[wid] = s; red[4 + wid] = s2; }
  __syncthreads();
  float S = red[0] + red[1] + red[2] + red[3];
  float S2 = red[4] + red[5] + red[6] + red[7];
  float mu = S * (1.f / CC);
  float rstd = rsqrtf(S2 * (1.f / CC) - mu * mu + EPS_);
#pragma unroll
  for (int j = 0; j < 4; ++j)
    ln_cf[t * 4 + j] = (x[j] - mu) * rstd * g[t * 4 + j] + be[t * 4 + j];
}

// ---- k0b: qvec[j] = ln_cf . Wq[j,:]   (one wave per j) ----
__global__ __launch_bounds__(256) void k0b(const float* __restrict__ ln_cf,
                                           const float* __restrict__ Wq,
                                           float* __restrict__ qvec) {
  int lane = threadIdx.x & 63;
  int j = blockIdx.x * 4 + (threadIdx.x >> 6);
  const float4* wr = (const float4*)(Wq + (size_t)j * CC);
  const float4* l4 = (const float4*)ln_cf;
  float a = 0.f;
#pragma unroll
  for (int k = 0; k < 4; ++k) {
    float4 w = wr[lane + 64 * k], l = l4[lane + 64 * k];
    a += w.x * l.x + w.y * l.y + w.z * l.z + w.w * l.w;
  }
  a = wsum(a);
  if (lane == 0) qvec[j] = a;
}

// ---- k0c: qW[h,c] = scale * sum_d qvec[h*D+d]*Wkv[h*D+d, c]; qWg = qW*gamma ----
__global__ __launch_bounds__(256) void k0c(const float* __restrict__ qvec,
                                           const float* __restrict__ Wkv,
                                           const float* __restrict__ kvg,
                                           float* __restrict__ qW,
                                           float* __restrict__ qWg) {
  int h = blockIdx.x >> 2;
  int c = ((blockIdx.x & 3) << 8) + threadIdx.x;
  float a = 0.f;
#pragma unroll 4
  for (int d = 0; d < DD; ++d)
    a += qvec[h * DD + d] * Wkv[((size_t)(h * DD + d)) * CC + c];
  a *= SCALE_;
  qW[h * CC + c] = a;
  qWg[h * CC + c] = a * kvg[c];
}

// ---- k0d: qWgs[h] = sum_c qWg[h,c];  qWb[h] = sum_c qW[h,c]*beta[c] ----
__global__ __launch_bounds__(256) void k0d(const float* __restrict__ qW,
                                           const float* __restrict__ qWg,
                                           const float* __restrict__ kvb,
                                           float* __restrict__ qWgs,
                                           float* __restrict__ qWb) {
  int h = blockIdx.x, t = threadIdx.x, lane = t & 63, wid = t >> 6;
  float gs = 0.f, bb = 0.f;
  for (int c = t; c < CC; c += 256) {
    gs += qWg[h * CC + c];
    bb += qW[h * CC + c] * kvb[c];
  }
  gs = wsum(gs);
  bb = wsum(bb);
  __shared__ float red[8];
  if (lane == 0) { red[wid] = gs; red[4 + wid] = bb; }
  __syncthreads();
  if (t == 0) {
    qWgs[h] = red[0] + red[1] + red[2] + red[3];
    qWb[h] = red[4] + red[5] + red[6] + red[7];
  }
}

// ---- k1: pass 1 over features: per row mu, rstd, 8 logits. One wave per row,
//          8 rows/wave, qWg staged in LDS (32 KB). ----
__global__ __launch_bounds__(256) void k1(const float* __restrict__ x,
                                          const float* __restrict__ qWg,
                                          const float* __restrict__ qWgs,
                                          const float* __restrict__ qWb,
                                          float* __restrict__ mu_o,
                                          float* __restrict__ rstd_o,
                                          float* __restrict__ logits) {
  __shared__ float lw[HH * CC]; // 32 KB
  int t = threadIdx.x, lane = t & 63, wid = t >> 6;
  {
    const float4* src = (const float4*)qWg;
    float4* dst = (float4*)lw;
    for (int i = t; i < HH * CC / 4; i += 256) dst[i] = src[i];
  }
  float qs[HH], qb[HH];
#pragma unroll
  for (int h = 0; h < HH; ++h) { qs[h] = qWgs[h]; qb[h] = qWb[h]; }
  __syncthreads();
  size_t base = (size_t)blockIdx.x * 32 + (size_t)wid * 8;
  const float4* lw4 = (const float4*)lw;
  for (int rr = 0; rr < 8; ++rr) {
    size_t r = base + rr;
    const float4* xr = (const float4*)(x + r * CC);
    float4 v[4];
#pragma unroll
    for (int k = 0; k < 4; ++k) v[k] = xr[lane + 64 * k];
    float s = 0.f, s2 = 0.f;
#pragma unroll
    for (int k = 0; k < 4; ++k) {
      s += v[k].x + v[k].y + v[k].z + v[k].w;
      s2 += v[k].x * v[k].x + v[k].y * v[k].y + v[k].z * v[k].z + v[k].w * v[k].w;
    }
    s = wsum(s);
    s2 = wsum(s2);
    float mu = s * (1.f / CC);
    float rstd = rsqrtf(s2 * (1.f / CC) - mu * mu + EPS_);
    float dt[HH];
#pragma unroll
    for (int h = 0; h < HH; ++h) {
      float a = 0.f;
#pragma unroll
      for (int k = 0; k < 4; ++k) {
        float4 q = lw4[h * 256 + lane + 64 * k];
        a += q.x * v[k].x + q.y * v[k].y + q.z * v[k].z + q.w * v[k].w;
      }
      dt[h] = a;
    }
#pragma unroll
    for (int h = 0; h < HH; ++h) dt[h] = wsum(dt[h]);
    if (lane == 0) {
      mu_o[r] = mu;
      rstd_o[r] = rstd;
      size_t b = r >> 12;
      int n = (int)(r & (NN - 1));
#pragma unroll
      for (int h = 0; h < HH; ++h)
        logits[((b * HH + h) << 12) + n] = rstd * (dt[h] - mu * qs[h]) + qb[h];
    }
  }
}

// ---- k2: per (b,h): lse = max + log(sum exp), u = sum p*rstd*mu ----
__global__ __launch_bounds__(256) void k2(const float* __restrict__ logits,
                                          const float* __restrict__ mu,
                                          const float* __restrict__ rstd,
                                          float* __restrict__ lse,
                                          float* __restrict__ u) {
  int bh = blockIdx.x, b = bh >> 3;
  int t = threadIdx.x, lane = t & 63, wid = t >> 6;
  const float4* lg = (const float4*)(logits + (size_t)bh * NN);
  float4 lv[4];
#pragma unroll
  for (int k = 0; k < 4; ++k) lv[k] = lg[t + 256 * k];
  float m = -3.4e38f;
#pragma unroll
  for (int k = 0; k < 4; ++k)
    m = fmaxf(m, fmaxf(fmaxf(lv[k].x, lv[k].y), fmaxf(lv[k].z, lv[k].w)));
  m = wmax(m);
  __shared__ float red[12];
  if (lane == 0) red[wid] = m;
  __syncthreads();
  m = fmaxf(fmaxf(red[0], red[1]), fmaxf(red[2], red[3]));
  const float4* mv4 = (const float4*)(mu + (size_t)b * NN);
  const float4* rv4 = (const float4*)(rstd + (size_t)b * NN);
  float e = 0.f, un = 0.f;
#pragma unroll
  for (int k = 0; k < 4; ++k) {
    float4 mv = mv4[t + 256 * k], rv = rv4[t + 256 * k];
    float p;
    p = __expf(lv[k].x - m); e += p; un += p * rv.x * mv.x;
    p = __expf(lv[k].y - m); e += p; un += p * rv.y * mv.y;
    p = __expf(lv[k].z - m); e += p; un += p * rv.z * mv.z;
    p = __expf(lv[k].w - m); e += p; un += p * rv.w * mv.w;
  }
  e = wsum(e);
  un = wsum(un);
  if (lane == 0) { red[4 + wid] = e; red[8 + wid] = un; }
  __syncthreads();
  if (t == 0) {
    float E = red[4] + red[5] + red[6] + red[7];
    float UN = red[8] + red[9] + red[10] + red[11];
    lse[bh] = m + logf(E);
    u[bh] = UN / E;
  }
}

// ---- k3: pass 2: partial t[b,h,c] over 128-row chunks. thread owns 4 cols,
//          8 heads -> 32 reg accumulators. ----
__global__ __launch_bounds__(256) void k3(const float* __restrict__ x,
                                          const float* __restrict__ logits,
                                          const float* __restrict__ lse,
                                          const float* __restrict__ rstd,
                                          float* __restrict__ part) {
  int b = blockIdx.y, ch = blockIdx.x, n0 = ch * 128, t = threadIdx.x;
  __shared__ float w[8 * 128]; // w[h*128+row] = p*rstd
  for (int idx = t; idx < 1024; idx += 256) {
    int h = idx >> 7, row = idx & 127;
    float l = logits[((size_t)(b * 8 + h) << 12) + n0 + row];
    w[idx] = __expf(l - lse[b * 8 + h]) * rstd[((size_t)b << 12) + n0 + row];
  }
  __syncthreads();
  float acc[8][4] = {};
  const float4* xb = (const float4*)x + ((size_t)(b * NN + n0)) * 256 + t;
#pragma unroll 4
  for (int row = 0; row < 128; ++row) {
    float4 xv = xb[(size_t)row * 256];
#pragma unroll
    for (int h = 0; h < 8; ++h) {
      float wh = w[h * 128 + row];
      acc[h][0] += wh * xv.x;
      acc[h][1] += wh * xv.y;
      acc[h][2] += wh * xv.z;
      acc[h][3] += wh * xv.w;
    }
  }
  float4* pp = (float4*)(part + ((size_t)(b * 32 + ch)) * 8192);
#pragma unroll
  for (int h = 0; h < 8; ++h)
    pp[h * 256 + t] = make_float4(acc[h][0], acc[h][1], acc[h][2], acc[h][3]);
}

// ---- k4: reduce 32 chunks -> s[b,h,c] = gamma*(t - u) + beta ----
__global__ __launch_bounds__(256) void k4(const float* __restrict__ part,
                                          const float* __restrict__ u,
                                          const float* __restrict__ kvg,
                                          const float* __restrict__ kvb,
                                          float* __restrict__ s) {
  int i = blockIdx.x * 256 + threadIdx.x;
  int b = i >> 13, j = i & 8191, h = j >> 10, c = j & 1023;
  float a = 0.f;
#pragma unroll 8
  for (int ch = 0; ch < 32; ++ch) a += part[((size_t)(b * 32 + ch) << 13) + j];
  s[i] = kvg[c] * (a - u[b * 8 + h]) + kvb[c];
}

// ---- k5: agg[b, j] = Wkv[C+j, :] . s[b, j/D, :]  (wave per j, loop b) ----
__global__ __launch_bounds__(256) void k5(const float* __restrict__ Wkv,
                                          const float* __restrict__ s,
                                          float* __restrict__ agg) {
  int lane = threadIdx.x & 63;
  int j = blockIdx.x * 4 + (threadIdx.x >> 6);
  int h = j >> 7;
  const float4* wr = (const float4*)(Wkv + ((size_t)(CC + j)) * CC);
  float4 wv[4];
#pragma unroll
  for (int k = 0; k < 4; ++k) wv[k] = wr[lane + 64 * k];
  for (int b = 0; b < BB; ++b) {
    const float4* s4 = (const float4*)(s + ((size_t)(b * 8 + h)) * 1024);
    float a = 0.f;
#pragma unroll
    for (int k = 0; k < 4; ++k) {
      float4 sv = s4[lane + 64 * k];
      a += wv[k].x * sv.x + wv[k].y * sv.y + wv[k].z * sv.z + wv[k].w * sv.w;
    }
    a = wsum(a);
    if (lane == 0) agg[b * CC + j] = a;
  }
}

// ---- k6: out[b,j] = cf[j] + agg[b,:] . proj_W[j,:] + proj_b[j] ----
__global__ __launch_bounds__(256) void k6(const float* __restrict__ pW,
                                          const float* __restrict__ agg,
                                          const float* __restrict__ cf,
                                          const float* __restrict__ pb,
                                          float* __restrict__ out) {
  int lane = threadIdx.x & 63;
  int j = blockIdx.x * 4 + (threadIdx.x >> 6);
  const float4* wr = (const float4*)(pW + (size_t)j * CC);
  float4 wv[4];
#pragma unroll
  for (int k = 0; k < 4; ++k) wv[k] = wr[lane + 64 * k];
  for (int b = 0; b < BB; ++b) {
    const float4* a4 = (const float4*)(agg + (size_t)b * CC);
    float a = 0.f;
#pragma unroll
    for (int k = 0; k < 4; ++k) {
      float4 av = a4[lane + 64 * k];
      a += wv[k].x * av.x + wv[k].y * av.y + wv[k].z * av.z + wv[k].w * av.w;
    }
    a = wsum(a);
    if (lane == 0) out[b * CC + j] = cf[j] + a + pb[j];
  }
}

// ws float offsets
constexpr size_t WS_LNCF = 0;                     // 1024
constexpr size_t WS_QVEC = 1024;                  // 1024
constexpr size_t WS_QW = 2048;                    // 8192
constexpr size_t WS_QWG = 10240;                  // 8192
constexpr size_t WS_QWGS = 18432;                 // 8
constexpr size_t WS_QWB = 18440;                  // 8
constexpr size_t WS_MU = 18448;                   // 65536
constexpr size_t WS_RSTD = 83984;                 // 65536
constexpr size_t WS_LOGIT = 149520;               // 524288
constexpr size_t WS_LSE = 673808;                 // 128
constexpr size_t WS_U = 673936;                   // 128
constexpr size_t WS_S = 674064;                   // 131072
constexpr size_t WS_AGG = 805136;                 // 16384
constexpr size_t WS_PART = 821520;                // 4194304 (16 MB)

extern "C" void kernel_launch(void* const* d_in, const int* in_sizes, int n_in,
                              void* d_out, int out_size, void* d_ws, size_t ws_size,
                              hipStream_t stream) {
  const float* cf = (const float*)d_in[0];
  const float* x = (const float*)d_in[1];
  const float* qg = (const float*)d_in[2];
  const float* qb = (const float*)d_in[3];
  const float* Wq = (const float*)d_in[4];
  const float* kvg = (const float*)d_in[5];
  const float* kvb = (const float*)d_in[6];
  const float* Wkv = (const float*)d_in[7];
  const float* pW = (const float*)d_in[8];
  const float* pb = (const float*)d_in[9];
  float* ws = (float*)d_ws;
  float* out = (float*)d_out;

  k0a<<<1, 256, 0, stream>>>(cf, qg, qb, ws + WS_LNCF);
  k0b<<<256, 256, 0, stream>>>(ws + WS_LNCF, Wq, ws + WS_QVEC);
  k0c<<<32, 256, 0, stream>>>(ws + WS_QVEC, Wkv, kvg, ws + WS_QW, ws + WS_QWG);
  k0d<<<8, 256, 0, stream>>>(ws + WS_QW, ws + WS_QWG, kvb, ws + WS_QWGS, ws + WS_QWB);
  k1<<<2048, 256, 0, stream>>>(x, ws + WS_QWG, ws + WS_QWGS, ws + WS_QWB,
                               ws + WS_MU, ws + WS_RSTD, ws + WS_LOGIT);
  k2<<<128, 256, 0, stream>>>(ws + WS_LOGIT, ws + WS_MU, ws + WS_RSTD,
                              ws + WS_LSE, ws + WS_U);
  k3<<<dim3(32, 16), 256, 0, stream>>>(x, ws + WS_LOGIT, ws + WS_LSE,
                                       ws + WS_RSTD, ws + WS_PART);
  k4<<<512, 256, 0, stream>>>(ws + WS_PART, ws + WS_U, kvg, kvb, ws + WS_S);
  k5<<<256, 256, 0, stream>>>(Wkv, ws + WS_S, ws + WS_AGG);
  k6<<<256, 256, 0, stream>>>(pW, ws + WS_AGG, cf, pb, out);
}